// Round 2
// baseline (221.712 us; speedup 1.0000x reference)
//
#include <hip/hip_runtime.h>

#define TAGS 256
#define RPW 4   // rows (256-tag vectors) per wave

typedef float f32x4 __attribute__((ext_vector_type(4)));  // native vec for nontemporal builtins

// One 64-lane wave processes RPW=4 rows.
// Phase 1: issue 4 independent 1 KiB row loads (MLP=4).
// Phase 2: per-row local argmax over 4 elems, then a value-only 6-step
//          shfl_xor max butterfly across 64 lanes (4 independent chains -> ILP).
// Phase 3: argmax index via __ballot(local_max == wave_max): the first set
//          lane holds the earliest max index (lane l owns tags [4l,4l+4),
//          strict '>' locally keeps the earliest) -> exact argmax tie-break.
// Phase 4: wave-uniform gather of transitions[row] (scalar base via
//          readfirstlane), add, nontemporal float4 store.
__global__ __launch_bounds__(256) void crf_head_kernel(
    const float* __restrict__ in,
    const float* __restrict__ trans,
    float* __restrict__ out,
    int rows)
{
    const int lane  = threadIdx.x & 63;
    const int gwave = blockIdx.x * (blockDim.x >> 6) + (threadIdx.x >> 6);

    const int r0 = gwave * RPW;
    if (r0 >= rows) return;

    int r[RPW];
#pragma unroll
    for (int i = 0; i < RPW; ++i) {
        int ri = r0 + i;
        r[i] = (ri < rows) ? ri : (rows - 1);   // tail clamp (rows%4==0 in practice)
    }

    // ---- Phase 1: 4 independent streaming loads in flight ----
    f32x4 v[RPW];
#pragma unroll
    for (int i = 0; i < RPW; ++i) {
        const f32x4* p = (const f32x4*)(in + (size_t)r[i] * TAGS);
        v[i] = __builtin_nontemporal_load(&p[lane]);
    }

    // ---- Phase 2: local argmax (strict > keeps earliest index) ----
    float lm[RPW]; int mi[RPW];
#pragma unroll
    for (int i = 0; i < RPW; ++i) {
        float mm = v[i].x; int ii = lane * 4;
        if (v[i].y > mm) { mm = v[i].y; ii = lane * 4 + 1; }
        if (v[i].z > mm) { mm = v[i].z; ii = lane * 4 + 2; }
        if (v[i].w > mm) { mm = v[i].w; ii = lane * 4 + 3; }
        lm[i] = mm; mi[i] = ii;
    }

    // value-only butterfly; 4 independent dependency chains interleave
    float wm[RPW];
#pragma unroll
    for (int i = 0; i < RPW; ++i) wm[i] = lm[i];
#pragma unroll
    for (int off = 32; off >= 1; off >>= 1) {
#pragma unroll
        for (int i = 0; i < RPW; ++i) {
            float om = __shfl_xor(wm[i], off, 64);
            wm[i] = fmaxf(wm[i], om);
        }
    }

    // ---- Phase 3: recover earliest argmax index (1 ballot + 1 shfl) ----
    int srow[RPW];
#pragma unroll
    for (int i = 0; i < RPW; ++i) {
        unsigned long long eq = __ballot(lm[i] == wm[i]);  // non-empty by construction
        int firstlane = __ffsll((long long)eq) - 1;        // lowest lane with the max
        int gmi = __shfl(mi[i], firstlane, 64);
        srow[i] = __builtin_amdgcn_readfirstlane(gmi);     // wave-uniform -> SGPR
    }

    // ---- Phase 4: gather transitions rows (L2-hot), add, stream out ----
    f32x4 t[RPW];
#pragma unroll
    for (int i = 0; i < RPW; ++i) {
        const f32x4* tp = (const f32x4*)(trans + (size_t)srow[i] * TAGS);
        t[i] = tp[lane];
    }

#pragma unroll
    for (int i = 0; i < RPW; ++i) {
        f32x4 o = v[i] + t[i];
        f32x4* op = (f32x4*)(out + (size_t)r[i] * TAGS);
        __builtin_nontemporal_store(o, &op[lane]);
    }
}

extern "C" void kernel_launch(void* const* d_in, const int* in_sizes, int n_in,
                              void* d_out, int out_size, void* d_ws, size_t ws_size,
                              hipStream_t stream) {
    const float* in    = (const float*)d_in[0];   // [B, T, TAGS] fp32
    const float* trans = (const float*)d_in[1];   // [TAGS, TAGS] fp32
    float* out = (float*)d_out;                   // [B, T, TAGS] fp32

    int rows  = in_sizes[0] / TAGS;               // B*T = 131072
    int waves = (rows + RPW - 1) / RPW;           // one wave per 4 rows
    int blocks = (waves + 3) / 4;                 // 4 waves (256 threads) per block
    crf_head_kernel<<<dim3(blocks), dim3(256), 0, stream>>>(in, trans, out, rows);
}